// Round 9
// baseline (125.514 us; speedup 1.0000x reference)
//
#include <hip/hip_runtime.h>

#define Bn 32
#define Tn 256
#define Cn 512
#define Ln 25

typedef _Float16 h8 __attribute__((ext_vector_type(8)));
typedef __attribute__((ext_vector_type(4))) float f32x4;

#define SCALE2LOG2E 2.885390081777927f   // 2*log2(e)

#if __has_builtin(__builtin_amdgcn_exp2f)
#define EXP2(x) __builtin_amdgcn_exp2f(x)
#else
#define EXP2(x) __expf(0.69314718056f * (x))
#endif

// sum across 16-lane groups on VALU pipe: xor1, xor2, xor7, xor15 pairings
#define DPP_ADD(v, ctrl) \
    ((v) + __int_as_float(__builtin_amdgcn_update_dpp(0, __float_as_int(v), ctrl, 0xf, 0xf, true)))

// K1: wf = A(fp32)·W(fp32)^T + bias via fp16 MFMA, in-register fp32->fp16 cvt.
// BM=128, BN=64, BK=32, 256 thr = 4 waves (2m x 2n, wave-tile 64x32).
// Double-buffered LDS, stride-40-half rows. Grid 8x64 = 512 blocks (2+ blk/CU).
#define BM 128
#define BN 64
#define BKh 32
#define LDST 40
__global__ __launch_bounds__(256, 4) void k_gemm(
        const float* __restrict__ A, const float* __restrict__ W,
        const float* __restrict__ bias, float* __restrict__ wf) {
    __shared__ _Float16 As[2][BM * LDST];   // 2 x 10.24 KB
    __shared__ _Float16 Ws[2][BN * LDST];   // 2 x 5.12 KB
    const int tid  = threadIdx.x;
    const int lane = tid & 63;
    const int wv   = tid >> 6;
    const int n0 = blockIdx.x * BN;
    const int m0 = blockIdx.y * BM;
    const int wm = (wv >> 1) * 64;
    const int wn = (wv & 1) * 32;
    const int r = lane & 15, q = lane >> 4;

    // staging: A has 512 16B-chunks/slab (thread handles tid, tid+256), W has 256.
    const int arow = tid >> 2;           // 0..63
    const int akc  = tid & 3;            // 8-half chunk in BK=32
    const float* gA0 = A + (size_t)(m0 + arow) * Cn + akc * 8;
    const float* gA1 = gA0 + (size_t)64 * Cn;
    const float* gW  = W + (size_t)(n0 + arow) * Cn + akc * 8;
    const int lofs = arow * LDST + akc * 8;

    f32x4 acc[4][2];
    #pragma unroll
    for (int mi = 0; mi < 4; ++mi)
        #pragma unroll
        for (int ni = 0; ni < 2; ++ni) acc[mi][ni] = (f32x4){0.f, 0.f, 0.f, 0.f};

    // prologue: slab 0 -> buf 0
    {
        float4 a00 = *(const float4*)gA0;
        float4 a01 = *(const float4*)(gA0 + 4);
        float4 a10 = *(const float4*)gA1;
        float4 a11 = *(const float4*)(gA1 + 4);
        float4 w0  = *(const float4*)gW;
        float4 w1  = *(const float4*)(gW + 4);
        h8 h0, h1, h2;
        h0[0]=(_Float16)a00.x; h0[1]=(_Float16)a00.y; h0[2]=(_Float16)a00.z; h0[3]=(_Float16)a00.w;
        h0[4]=(_Float16)a01.x; h0[5]=(_Float16)a01.y; h0[6]=(_Float16)a01.z; h0[7]=(_Float16)a01.w;
        h1[0]=(_Float16)a10.x; h1[1]=(_Float16)a10.y; h1[2]=(_Float16)a10.z; h1[3]=(_Float16)a10.w;
        h1[4]=(_Float16)a11.x; h1[5]=(_Float16)a11.y; h1[6]=(_Float16)a11.z; h1[7]=(_Float16)a11.w;
        h2[0]=(_Float16)w0.x;  h2[1]=(_Float16)w0.y;  h2[2]=(_Float16)w0.z;  h2[3]=(_Float16)w0.w;
        h2[4]=(_Float16)w1.x;  h2[5]=(_Float16)w1.y;  h2[6]=(_Float16)w1.z;  h2[7]=(_Float16)w1.w;
        *(h8*)&As[0][lofs]            = h0;
        *(h8*)&As[0][64 * LDST + lofs] = h1;
        *(h8*)&Ws[0][lofs]            = h2;
    }
    __syncthreads();

    for (int kt = 0; kt < Cn / BKh; ++kt) {
        const int cur = kt & 1;
        float4 a00, a01, a10, a11, w0, w1;
        const bool more = (kt < Cn / BKh - 1);
        if (more) {
            const int ko = (kt + 1) * BKh;
            a00 = *(const float4*)(gA0 + ko);
            a01 = *(const float4*)(gA0 + ko + 4);
            a10 = *(const float4*)(gA1 + ko);
            a11 = *(const float4*)(gA1 + ko + 4);
            w0  = *(const float4*)(gW + ko);
            w1  = *(const float4*)(gW + ko + 4);
        }

        h8 af[4], bf[2];
        #pragma unroll
        for (int mi = 0; mi < 4; ++mi)
            af[mi] = *(const h8*)&As[cur][(wm + mi * 16 + r) * LDST + q * 8];
        #pragma unroll
        for (int ni = 0; ni < 2; ++ni)
            bf[ni] = *(const h8*)&Ws[cur][(wn + ni * 16 + r) * LDST + q * 8];
        #pragma unroll
        for (int mi = 0; mi < 4; ++mi)
            #pragma unroll
            for (int ni = 0; ni < 2; ++ni)
                acc[mi][ni] = __builtin_amdgcn_mfma_f32_16x16x32_f16(
                    af[mi], bf[ni], acc[mi][ni], 0, 0, 0);

        if (more) {
            h8 h0, h1, h2;
            h0[0]=(_Float16)a00.x; h0[1]=(_Float16)a00.y; h0[2]=(_Float16)a00.z; h0[3]=(_Float16)a00.w;
            h0[4]=(_Float16)a01.x; h0[5]=(_Float16)a01.y; h0[6]=(_Float16)a01.z; h0[7]=(_Float16)a01.w;
            h1[0]=(_Float16)a10.x; h1[1]=(_Float16)a10.y; h1[2]=(_Float16)a10.z; h1[3]=(_Float16)a10.w;
            h1[4]=(_Float16)a11.x; h1[5]=(_Float16)a11.y; h1[6]=(_Float16)a11.z; h1[7]=(_Float16)a11.w;
            h2[0]=(_Float16)w0.x;  h2[1]=(_Float16)w0.y;  h2[2]=(_Float16)w0.z;  h2[3]=(_Float16)w0.w;
            h2[4]=(_Float16)w1.x;  h2[5]=(_Float16)w1.y;  h2[6]=(_Float16)w1.z;  h2[7]=(_Float16)w1.w;
            const int nxt = cur ^ 1;
            *(h8*)&As[nxt][lofs]             = h0;
            *(h8*)&As[nxt][64 * LDST + lofs] = h1;
            *(h8*)&Ws[nxt][lofs]             = h2;
        }
        __syncthreads();
    }

    #pragma unroll
    for (int ni = 0; ni < 2; ++ni) {
        const float bv = bias[n0 + wn + ni * 16 + r];
        #pragma unroll
        for (int mi = 0; mi < 4; ++mi)
            #pragma unroll
            for (int reg = 0; reg < 4; ++reg) {
                int row = m0 + wm + mi * 16 + q * 4 + reg;
                int col = n0 + wn + ni * 16 + r;
                wf[(size_t)row * Cn + col] = acc[mi][ni][reg] + bv;
            }
    }
}

// K2: scores[b][l][t] = sum_c tanh(wf+pos)*aw = sum(aw) - 2*sum(aw*logistic)
// 512 thr = 8 waves: wave = (t_local 0..3) x (c-half 0..1); 4 c-elems/lane.
// 5x5 unrolled l-loop: 5 pos loads in flight, 5 independent compute+DPP chains.
__global__ __launch_bounds__(512) void k_scores(
        const float* __restrict__ wf, const float* __restrict__ pos,
        const float* __restrict__ aw, float* __restrict__ scores) {
    __shared__ float part[4 * Ln * 8];       // 3.2 KB
    const int tid  = threadIdx.x;
    const int lane = tid & 63;
    const int wv   = tid >> 6;
    const int tl   = wv >> 1;                // local t 0..3
    const int ch   = wv & 1;                 // c half
    const int t    = blockIdx.x * 4 + tl;
    const int b    = blockIdx.y;
    const int co   = ch * 256 + lane * 4;

    float4 w = *(const float4*)&wf[(b * Tn + t) * Cn + co];
    w.x *= SCALE2LOG2E; w.y *= SCALE2LOG2E; w.z *= SCALE2LOG2E; w.w *= SCALE2LOG2E;
    const float4 a = *(const float4*)&aw[co];
    const float U = (a.x + a.y) + (a.z + a.w);
    float4 u;
    u.x = -2.f * a.x; u.y = -2.f * a.y; u.z = -2.f * a.z; u.w = -2.f * a.w;

    const float* pp = pos + co;
    float* prt = &part[tl * Ln * 8 + ch * 4 + (lane >> 4)];
    const bool writer = ((lane & 15) == 0);

    #pragma unroll
    for (int lo = 0; lo < 5; ++lo) {
        float4 pv[5];
        #pragma unroll
        for (int j = 0; j < 5; ++j)
            pv[j] = *(const float4*)(pp + (lo * 5 + j) * Cn);
        #pragma unroll
        for (int j = 0; j < 5; ++j) {
            const float4 p = pv[j];
            float s = U;
            s = fmaf(u.x, __builtin_amdgcn_rcpf(1.f + EXP2(fmaf(SCALE2LOG2E, p.x, w.x))), s);
            s = fmaf(u.y, __builtin_amdgcn_rcpf(1.f + EXP2(fmaf(SCALE2LOG2E, p.y, w.y))), s);
            s = fmaf(u.z, __builtin_amdgcn_rcpf(1.f + EXP2(fmaf(SCALE2LOG2E, p.z, w.z))), s);
            s = fmaf(u.w, __builtin_amdgcn_rcpf(1.f + EXP2(fmaf(SCALE2LOG2E, p.w, w.w))), s);
            s = DPP_ADD(s, 0xB1);    // xor 1
            s = DPP_ADD(s, 0x4E);    // xor 2
            s = DPP_ADD(s, 0x141);   // row_half_mirror (xor 7)
            s = DPP_ADD(s, 0x140);   // row_mirror (xor 15)
            if (writer) prt[(lo * 5 + j) * 8] = s;
        }
    }
    __syncthreads();
    if (tid < 4 * Ln) {
        int tl2 = tid / Ln, l2 = tid - tl2 * Ln;
        const float* q = &part[(tl2 * Ln + l2) * 8];
        float v = ((q[0] + q[1]) + (q[2] + q[3])) + ((q[4] + q[5]) + (q[6] + q[7]));
        scores[(b * Ln + l2) * Tn + blockIdx.x * 4 + tl2] = v;
    }
}

// K3: softmax over t; out[b][l][c] = sum_t p[l][t] * wf[b][t][c]
// 512 threads (8 waves), block per (c-chunk of 64, b).
__global__ __launch_bounds__(512) void k_pvam(
        const float* __restrict__ wf, const float* __restrict__ scores,
        float* __restrict__ out) {
    __shared__ float buf[8 * Ln * 64];       // 51.2 KB: scores staging, then reduction
    __shared__ float pT[Tn][28];             // 28.7 KB
    const int tid = threadIdx.x;
    const int cx  = blockIdx.x;
    const int b   = blockIdx.y;

    const float* sc = scores + b * Ln * Tn;
    for (int i = tid * 4; i < Ln * Tn; i += 2048)
        *(float4*)&buf[i] = *(const float4*)&sc[i];
    __syncthreads();

    const int lane = tid & 63;
    const int wv   = tid >> 6;

    for (int l = wv; l < Ln; l += 8) {
        float v0 = buf[l * Tn + lane];
        float v1 = buf[l * Tn + 64 + lane];
        float v2 = buf[l * Tn + 128 + lane];
        float v3 = buf[l * Tn + 192 + lane];
        float m = fmaxf(fmaxf(v0, v1), fmaxf(v2, v3));
        #pragma unroll
        for (int o = 32; o > 0; o >>= 1) m = fmaxf(m, __shfl_xor(m, o));
        float e0 = __expf(v0 - m), e1 = __expf(v1 - m);
        float e2 = __expf(v2 - m), e3 = __expf(v3 - m);
        float s = e0 + e1 + e2 + e3;
        #pragma unroll
        for (int o = 32; o > 0; o >>= 1) s += __shfl_xor(s, o);
        float rs = __builtin_amdgcn_rcpf(s);
        pT[lane][l]       = e0 * rs;
        pT[64 + lane][l]  = e1 * rs;
        pT[128 + lane][l] = e2 * rs;
        pT[192 + lane][l] = e3 * rs;
    }
    __syncthreads();

    const int c = cx * 64 + lane;
    float acc[Ln];
    #pragma unroll
    for (int l = 0; l < Ln; ++l) acc[l] = 0.f;

    const float* wfp = wf + (b * Tn + wv * 32) * Cn + c;
    for (int tt = 0; tt < 32; ++tt) {
        float w = wfp[tt * Cn];
        const float* pp = &pT[wv * 32 + tt][0];
        float p[Ln];
        *(float4*)&p[0]  = *(const float4*)&pp[0];
        *(float4*)&p[4]  = *(const float4*)&pp[4];
        *(float4*)&p[8]  = *(const float4*)&pp[8];
        *(float4*)&p[12] = *(const float4*)&pp[12];
        *(float4*)&p[16] = *(const float4*)&pp[16];
        *(float4*)&p[20] = *(const float4*)&pp[20];
        p[24] = pp[24];
        #pragma unroll
        for (int l = 0; l < Ln; ++l) acc[l] = fmaf(p[l], w, acc[l]);
    }

    __syncthreads();
    #pragma unroll
    for (int l = 0; l < Ln; ++l)
        buf[(wv * Ln + l) * 64 + lane] = acc[l];
    __syncthreads();
    for (int idx = tid; idx < Ln * 64; idx += 512) {
        int l = idx >> 6, cc = idx & 63;
        float v = 0.f;
        #pragma unroll
        for (int w = 0; w < 8; ++w) v += buf[(w * Ln + l) * 64 + cc];
        out[(b * Ln + l) * Cn + cx * 64 + cc] = v;
    }
}

extern "C" void kernel_launch(void* const* d_in, const int* in_sizes, int n_in,
                              void* d_out, int out_size, void* d_ws, size_t ws_size,
                              hipStream_t stream) {
    const float* A    = (const float*)d_in[0];
    const float* W    = (const float*)d_in[1];
    const float* bias = (const float*)d_in[2];
    const float* pos  = (const float*)d_in[3];
    const float* aw   = (const float*)d_in[4];

    char* ws = (char*)d_ws;
    float* wf     = (float*)ws;                          // 16.78 MB
    float* scores = (float*)(ws + 16777216ull);          // 0.82 MB
    float* out = (float*)d_out;

    k_gemm<<<dim3(Cn / BN, (Bn * Tn) / BM), 256, 0, stream>>>(A, W, bias, wf);
    k_scores<<<dim3(Tn / 4, Bn), 512, 0, stream>>>(wf, pos, aw, scores);
    k_pvam<<<dim3(Cn / 64, Bn), 512, 0, stream>>>(wf, scores, out);
}